// Round 4
// baseline (282.244 us; speedup 1.0000x reference)
//
#include <hip/hip_runtime.h>
#include <hip/hip_bf16.h>
#include <stdint.h>

// x:(4,2048,1024)f32, Wq/Wk/Wv:(1024,1024)f32 -> out:(4,2048,1024)f32
// Pipeline: cvt->bf16 | merged QKV GEMM (V cols stored transposed) |
//   QK^T GEMM fused exp + atomic rowsum (bf16 E) | invert rowsum |
//   E@V^T GEMM with per-row 1/sum scaling -> f32 out.
// GEMM core: 256x256 tile, BK=64, 8 waves (2x4), 8-phase counted-vmcnt
// schedule (T2 swizzle + T3/T4 + T5 setprio), 128KiB static LDS.

typedef short bf16x8 __attribute__((ext_vector_type(8)));
typedef float f32x4  __attribute__((ext_vector_type(4)));

__device__ __forceinline__ unsigned short f2bf(float f) {
  unsigned u = __float_as_uint(f);
  u += 0x7fff + ((u >> 16) & 1);  // RNE; finite inputs
  return (unsigned short)(u >> 16);
}

__global__ __launch_bounds__(256) void cvt_bf16(const float* __restrict__ src,
                                                unsigned short* __restrict__ dst) {
  int i = (blockIdx.x * 256 + threadIdx.x) * 4;
  float4 v = *(const float4*)(src + i);
  ushort4 o;
  o.x = f2bf(v.x); o.y = f2bf(v.y); o.z = f2bf(v.z); o.w = f2bf(v.w);
  *(ushort4*)(dst + i) = o;
}

__global__ __launch_bounds__(256) void cvt_w3(const float* __restrict__ q,
                                              const float* __restrict__ k,
                                              const float* __restrict__ v,
                                              unsigned short* __restrict__ dst) {
  int b = blockIdx.x;                       // 0..3071 = stacked row
  const float* s = (b < 1024) ? q : (b < 2048) ? k : v;
  int off = (b & 1023) * 1024 + threadIdx.x * 4;
  float4 x = *(const float4*)(s + off);
  ushort4 o;
  o.x = f2bf(x.x); o.y = f2bf(x.y); o.z = f2bf(x.z); o.w = f2bf(x.w);
  *(ushort4*)(dst + b * 1024 + threadIdx.x * 4) = o;
}

__global__ __launch_bounds__(256) void invert8k(float* __restrict__ p) {
  int i = blockIdx.x * 256 + threadIdx.x;
  p[i] = 1.0f / p[i];
}

__device__ __forceinline__ void gl16(const unsigned short* g, char* l) {
  __builtin_amdgcn_global_load_lds(
      (const __attribute__((address_space(1))) unsigned int*)g,
      (__attribute__((address_space(3))) unsigned int*)l, 16, 0, 0);
}

#define BAR() __builtin_amdgcn_s_barrier()
#define VMC(n) asm volatile("s_waitcnt vmcnt(" #n ")" ::: "memory")

// NT GEMM 256x256xK, C[m][n] = sum_k A[m][k]*B[n][k], A/B bf16 K-contig.
// STORE 0: QKV  (o0 = QK bf16 [2][8192][1024], o1 = Vt bf16 [4][1024][2048])
// STORE 1: EXP  (o0 = E bf16 [2048][2048] per bz, o1 = rowsum f32, atomic)
// STORE 2: PV   (o0 = out f32 per bz, o1 = rowinv f32 per bz)
template<int STORE>
__global__ __launch_bounds__(512, 2) void gemm8(
    const unsigned short* __restrict__ A, const unsigned short* __restrict__ B,
    long sA, long sB, int lda, int ldb, int K,
    void* __restrict__ o0, void* __restrict__ o1) {
  __shared__ __align__(16) char smem[131072];  // slot(64K) x {A(32K: lo,hi), B(32K)}
  const int tid = threadIdx.x, lane = tid & 63, wid = tid >> 6;
  const int wm = wid >> 2, wn = wid & 3;  // 2 x 4 waves
  const int bz = blockIdx.z;
  const unsigned short* Ab = A + (size_t)bz * sA;
  const unsigned short* Bb = B + (size_t)bz * sB;
  const int row0 = blockIdx.x << 8, col0 = blockIdx.y << 8;

  // ---- staging constants (half-tile = 128 rows x 64k = 16KB = 1024 chunks)
  // chunk q = c*512 + wid*64 + lane -> r_local = q>>3, kc_lds = lane&7,
  // global chunk kc_g = kc_lds ^ (r_local&7)  (pre-swizzled source, linear LDS)
  const int sgr = wid * 8 + (lane >> 3);
  const int sgk = ((lane & 7) ^ (lane >> 3)) * 8;
  const int sgl = (wid * 64 + lane) * 16;
  const unsigned short* pS[4];
  pS[0] = Ab + (size_t)(row0 + sgr) * lda + sgk;  // A-lo
  pS[1] = Bb + (size_t)(col0 + sgr) * ldb + sgk;  // B-lo
  pS[2] = pS[0] + (size_t)128 * lda;              // A-hi
  pS[3] = pS[1] + (size_t)128 * ldb;              // B-hi
  const int hOff[4] = {0, 32768, 16384, 49152};

  auto STG = [&](int h, int t) {  // stage half-tile h of K-tile t (2 loads)
    char* d = smem + ((t & 1) << 16) + hOff[h] + sgl;
    const unsigned short* s = pS[h] + t * 64;
    int ld = (h & 1) ? ldb : lda;
    gl16(s, d);
    gl16(s + (size_t)64 * ld, d + 8192);
  };

  // ---- fragment reads (read-side swizzle = same involution kc^(row&7))
  bf16x8 aF[4][2], bF[2][2];
  const int aBase = (wm * 64 + (lane & 15)) * 128;
  const int bBase = (wn * 32 + (lane & 15)) * 128;
  const int k0off = (((lane >> 4) ^ (lane & 7))) * 16;
  const int k1off = (((4 + (lane >> 4)) ^ (lane & 7))) * 16;
  auto RDA = [&](int slot, int mh) {
#pragma unroll
    for (int im = 0; im < 4; ++im) {
      const char* p = smem + (slot << 16) + mh * 16384 + aBase + im * 2048;
      aF[im][0] = *(const bf16x8*)(p + k0off);
      aF[im][1] = *(const bf16x8*)(p + k1off);
    }
  };
  auto RDB = [&](int slot, int nh) {
#pragma unroll
    for (int in = 0; in < 2; ++in) {
      const char* p = smem + (slot << 16) + 32768 + nh * 16384 + bBase + in * 2048;
      bF[in][0] = *(const bf16x8*)(p + k0off);
      bF[in][1] = *(const bf16x8*)(p + k1off);
    }
  };

  f32x4 acc[8][4];
#pragma unroll
  for (int im = 0; im < 8; ++im)
#pragma unroll
    for (int in = 0; in < 4; ++in) acc[im][in] = f32x4{0.f, 0.f, 0.f, 0.f};

  auto MM = [&](int mh, int nh) {  // one C-quadrant x K=64: 16 MFMA
    __builtin_amdgcn_s_setprio(1);
#pragma unroll
    for (int im = 0; im < 4; ++im)
#pragma unroll
      for (int in = 0; in < 2; ++in) {
        f32x4& c = acc[mh * 4 + im][nh * 2 + in];
        c = __builtin_amdgcn_mfma_f32_16x16x32_bf16(aF[im][0], bF[in][0], c, 0, 0, 0);
        c = __builtin_amdgcn_mfma_f32_16x16x32_bf16(aF[im][1], bF[in][1], c, 0, 0, 0);
      }
    __builtin_amdgcn_s_setprio(0);
  };

  // ---- prologue: tile0 all 4 halves + tile1 {BL,AH,BH}; keep last 3 in flight
  STG(0, 0); STG(1, 0); STG(2, 0); STG(3, 0);
  STG(1, 1); STG(2, 1); STG(3, 1);
  VMC(6);
  BAR();

  const int NI = K >> 7;  // iterations, 2 K-tiles each (even tiles slot0, odd slot1)
  for (int i = 0; i < NI - 1; ++i) {
    const int t1 = 2 * i + 1, t2 = 2 * i + 2, t3 = 2 * i + 3;
    // P1..P4: compute tile t0 (slot0); stage AL(t1) then t2's {BL,AH,BH}
    RDA(0, 0); RDB(0, 0); STG(0, t1); BAR(); MM(0, 0); BAR();
    RDA(0, 1);            STG(1, t2); BAR(); MM(1, 0); BAR();
    RDB(0, 1);            STG(2, t2); BAR(); MM(1, 1); BAR();
    RDA(0, 0);            STG(3, t2); VMC(6); BAR(); MM(0, 1); BAR();
    // P5..P8: compute tile t1 (slot1); stage AL(t2) then t3's {BL,AH,BH}
    RDA(1, 0); RDB(1, 0); STG(0, t2); BAR(); MM(0, 0); BAR();
    RDA(1, 1);            STG(1, t3); BAR(); MM(1, 0); BAR();
    RDB(1, 1);            STG(2, t3); BAR(); MM(1, 1); BAR();
    RDA(1, 0);            STG(3, t3); VMC(6); BAR(); MM(0, 1); BAR();
  }
  {  // final iteration: only AL(t1) still to stage; drain at P4
    const int t1 = 2 * NI - 1;
    RDA(0, 0); RDB(0, 0); STG(0, t1); BAR(); MM(0, 0); BAR();
    RDA(0, 1); BAR(); MM(1, 0); BAR();
    RDB(0, 1); BAR(); MM(1, 1); BAR();
    RDA(0, 0); VMC(0); BAR(); MM(0, 1); BAR();
    RDA(1, 0); RDB(1, 0); BAR(); MM(0, 0); BAR();
    RDA(1, 1); BAR(); MM(1, 0); BAR();
    RDB(1, 1); BAR(); MM(1, 1); BAR();
    RDA(1, 0); BAR(); MM(0, 1);
  }

  // ---- epilogue. C/D: col=lane&15, row=(lane>>4)*4+j (m89-verified).
  const int rj = (lane >> 4) * 4;
  const int cl = lane & 15;
  if constexpr (STORE == 0) {
    unsigned short* QK = (unsigned short*)o0;
    unsigned short* Vt = (unsigned short*)o1;
#pragma unroll
    for (int im = 0; im < 8; ++im) {
      int rg = row0 + wm * 64 + (im & 3) * 16 + (im >> 2) * 128 + rj;
#pragma unroll
      for (int in = 0; in < 4; ++in) {
        int cg = col0 + wn * 32 + (in & 1) * 16 + (in >> 1) * 128 + cl;
#pragma unroll
        for (int j = 0; j < 4; ++j) {
          int r = rg + j;
          unsigned short bv = f2bf(acc[im][in][j]);
          if (cg < 2048) {  // Q (cg<1024) / K — block-uniform branch
            QK[(size_t)(cg >> 10) * 8388608 + (size_t)r * 1024 + (cg & 1023)] = bv;
          } else {          // V transposed: [b][o][s]
            Vt[(size_t)(r >> 11) * 2097152 + (size_t)(cg - 2048) * 2048 + (r & 2047)] = bv;
          }
        }
      }
    }
  } else if constexpr (STORE == 1) {
    unsigned short* E = (unsigned short*)o0 + (size_t)bz * 4194304;
    float* rs = (float*)o1 + bz * 2048;
    const float SC = 0.04508422003f;  // log2(e)/32
#pragma unroll
    for (int im = 0; im < 8; ++im) {
      int rg = row0 + wm * 64 + (im & 3) * 16 + (im >> 2) * 128 + rj;
#pragma unroll
      for (int j = 0; j < 4; ++j) {
        int r = rg + j;
        float part = 0.f;
#pragma unroll
        for (int in = 0; in < 4; ++in) {
          int cg = col0 + wn * 32 + (in & 1) * 16 + (in >> 1) * 128 + cl;
          unsigned short eb = f2bf(exp2f(acc[im][in][j] * SC));
          E[(size_t)r * 2048 + cg] = eb;
          part += __uint_as_float((unsigned)eb << 16);  // sum rounded values
        }
#pragma unroll
        for (int o = 1; o < 16; o <<= 1) part += __shfl_xor(part, o);
        if (cl == 0) atomicAdd(&rs[r], part);
      }
    }
  } else {
    float* O = (float*)o0 + (size_t)bz * 2097152;
    const float* ri = (const float*)o1 + bz * 2048;
#pragma unroll
    for (int im = 0; im < 8; ++im) {
      int rg = row0 + wm * 64 + (im & 3) * 16 + (im >> 2) * 128 + rj;
#pragma unroll
      for (int j = 0; j < 4; ++j) {
        float inv = ri[rg + j];
#pragma unroll
        for (int in = 0; in < 4; ++in) {
          int cg = col0 + wn * 32 + (in & 1) * 16 + (in >> 1) * 128 + cl;
          O[(size_t)(rg + j) * 1024 + cg] = acc[im][in][j] * inv;
        }
      }
    }
  }
}

extern "C" void kernel_launch(void* const* d_in, const int* in_sizes, int n_in,
                              void* d_out, int out_size, void* d_ws, size_t ws_size,
                              hipStream_t stream) {
  const float* x  = (const float*)d_in[0];
  const float* Wq = (const float*)d_in[1];
  const float* Wk = (const float*)d_in[2];
  const float* Wv = (const float*)d_in[3];

  char* w = (char*)d_ws;
  // ws: xb 16M | W3 6M | Q 16M | K 16M | Vt 16M | E 32M | rowsum 32K  (~102MB)
  unsigned short* xb = (unsigned short*)(w);
  unsigned short* W3 = (unsigned short*)(w + (16ull << 20));
  unsigned short* QK = (unsigned short*)(w + (22ull << 20));  // Q then K
  unsigned short* Vt = (unsigned short*)(w + (54ull << 20));
  unsigned short* E  = (unsigned short*)(w + (70ull << 20));
  float*          rs = (float*)        (w + (102ull << 20));

  hipMemsetAsync(rs, 0, 8192 * sizeof(float), stream);
  cvt_bf16<<<8192, 256, 0, stream>>>(x, xb);
  cvt_w3<<<3072, 256, 0, stream>>>(Wq, Wk, Wv, W3);

  // QKV: [8192x1024] @ [3072x1024]^T
  gemm8<0><<<dim3(32, 12, 1), 512, 0, stream>>>(
      xb, W3, 0, 0, 1024, 1024, 1024, QK, Vt);
  // scores+exp: per batch Q[2048x1024] @ K^T, E bf16 + rowsum
  gemm8<1><<<dim3(8, 8, 4), 512, 0, stream>>>(
      QK, QK + 8388608, 2097152, 2097152, 1024, 1024, 1024, E, rs);
  invert8k<<<32, 256, 0, stream>>>(rs);
  // out = E @ Vt, scaled by 1/rowsum
  gemm8<2><<<dim3(8, 4, 4), 512, 0, stream>>>(
      E, Vt, 4194304, 2097152, 2048, 2048, 2048, d_out, rs);
}

// Round 10
// 257.571 us; speedup vs baseline: 1.0958x; 1.0958x over previous
//
#include <hip/hip_runtime.h>
#include <hip/hip_bf16.h>
#include <stdint.h>

// x:(4,2048,1024)f32, Wq/Wk/Wv:(1024,1024)f32 -> out:(4,2048,1024)f32
// Pipeline: cvt->bf16 | Q/K proj GEMM | V proj GEMM (stored transposed) |
//   QK^T GEMM with fused exp2 + atomic rowsum (bf16 E) | invert rowsum |
//   E@V^T GEMM scaled by 1/rowsum -> f32 out.
// GEMM core: proven round-2 structure — 128x128 tile, BK=32, 4 waves,
// global_load_lds w16, chunk-XOR swizzle, double-buffered LDS, 4-5 blocks/CU.

typedef short bf16x8 __attribute__((ext_vector_type(8)));
typedef float f32x4  __attribute__((ext_vector_type(4)));

__device__ __forceinline__ unsigned short f2bf(float f) {
  unsigned u = __float_as_uint(f);
  u += 0x7fff + ((u >> 16) & 1);   // RNE; inputs are finite
  return (unsigned short)(u >> 16);
}

__global__ __launch_bounds__(256) void cvt_bf16(const float* __restrict__ src,
                                                unsigned short* __restrict__ dst) {
  int i = (blockIdx.x * 256 + threadIdx.x) * 4;
  float4 v = *(const float4*)(src + i);
  ushort4 o;
  o.x = f2bf(v.x); o.y = f2bf(v.y); o.z = f2bf(v.z); o.w = f2bf(v.w);
  *(ushort4*)(dst + i) = o;
}

__global__ __launch_bounds__(256) void invert8k(float* __restrict__ p) {
  int i = blockIdx.x * 256 + threadIdx.x;
  p[i] = 1.0f / p[i];
}

__device__ __forceinline__ void gload_lds16(const void* g, void* l) {
  __builtin_amdgcn_global_load_lds(
      (const __attribute__((address_space(1))) unsigned int*)g,
      (__attribute__((address_space(3))) unsigned int*)l, 16, 0, 0);
}

// NT GEMM: C[m][n] = sum_k A[m][k]*B[n][k]; A,B bf16 row-major K-contig.
// Tile 128x128, BK=32, 4 waves (2x2 of 64x64), 16x16x32 MFMA.
// LDS chunk swizzle: 16B chunk kg stored at kg ^ ((row>>1)&3) (pre-swizzled src).
// STORE 0: bf16 row-major (+bz*strideC)                         [Q/K proj]
// STORE 2: bf16 transposed per batch: [(r>>11)*1024+c][r&2047]  [V proj]
// STORE 3: E = bf16(exp2(acc*SC)) + atomic rowsum into aux      [scores]
// STORE 4: f32 row-major (+bz*strideC), scaled by aux[r]        [PV]
template<int STORE>
__global__ __launch_bounds__(256, 2) void gemm_nt(
    const unsigned short* __restrict__ A, const unsigned short* __restrict__ B,
    void* __restrict__ Cv, float* __restrict__ aux, int lda, int ldb, int ldc, int K,
    long strideA, long strideB, long strideC) {
  __shared__ __align__(16) unsigned short lds[2][2][128 * 32];
  const int tid  = threadIdx.x;
  const int lane = tid & 63;
  const int wid  = tid >> 6;
  const int bz   = blockIdx.z;
  const unsigned short* Ab = A + (size_t)bz * strideA;
  const unsigned short* Bb = B + (size_t)bz * strideB;
  const int row0 = blockIdx.x * 128;
  const int col0 = blockIdx.y * 128;

  f32x4 acc[4][4];
#pragma unroll
  for (int m = 0; m < 4; ++m)
#pragma unroll
    for (int n = 0; n < 4; ++n) acc[m][n] = f32x4{0.f, 0.f, 0.f, 0.f};

  const int KT = K >> 5;

  auto stage = [&](int buf, int kt) {
    const int k0 = kt << 5;
#pragma unroll
    for (int it = 0; it < 2; ++it) {
      int j   = it * 256 + tid;       // 512 chunks of 16B per operand tile
      int r   = j >> 2;               // tile row 0..127
      int kg  = j & 3;                // 16B chunk within row
      int kgS = kg ^ ((r >> 1) & 3);  // pre-swizzled global source (LDS stays linear)
      gload_lds16(Ab + (size_t)(row0 + r) * lda + k0 + kgS * 8, &lds[buf][0][j * 8]);
      gload_lds16(Bb + (size_t)(col0 + r) * ldb + k0 + kgS * 8, &lds[buf][1][j * 8]);
    }
  };

  stage(0, 0);
  int buf = 0;
  for (int kt = 0; kt < KT; ++kt) {
    __syncthreads();  // drains vmcnt for staged buf; also guards re-stage of other buf
    if (kt + 1 < KT) stage(buf ^ 1, kt + 1);
    const unsigned short* As = &lds[buf][0][0];
    const unsigned short* Bs = &lds[buf][1][0];
    const int kg = lane >> 4;
    const int lr = lane & 15;
    bf16x8 af[4], bfr[4];
#pragma unroll
    for (int m = 0; m < 4; ++m) {
      int r = ((wid >> 1) * 64) + m * 16 + lr;
      af[m] = *(const bf16x8*)(As + r * 32 + ((kg ^ ((r >> 1) & 3)) * 8));
    }
#pragma unroll
    for (int n = 0; n < 4; ++n) {
      int c = ((wid & 1) * 64) + n * 16 + lr;
      bfr[n] = *(const bf16x8*)(Bs + c * 32 + ((kg ^ ((c >> 1) & 3)) * 8));
    }
#pragma unroll
    for (int m = 0; m < 4; ++m)
#pragma unroll
      for (int n = 0; n < 4; ++n)
        acc[m][n] = __builtin_amdgcn_mfma_f32_16x16x32_bf16(af[m], bfr[n], acc[m][n], 0, 0, 0);
    buf ^= 1;
  }

  // Epilogue. C/D layout: col = lane&15, row = (lane>>4)*4 + j  [m89-verified]
  const int wr0 = row0 + (wid >> 1) * 64;
  const int wc0 = col0 + (wid & 1) * 64;
  const int rj  = lane >> 4;
  const int cl  = lane & 15;
  if constexpr (STORE == 3) {
    // scores: E[r][c] = bf16(exp2(acc * log2e/32)); rowsum += sum of rounded E
    unsigned short* E = (unsigned short*)Cv + (size_t)bz * 4194304;
    float* rs = aux + bz * 2048;
    const float SC = 0.045084220027780106f;  // log2(e)/32
#pragma unroll
    for (int m = 0; m < 4; ++m) {
#pragma unroll
      for (int j = 0; j < 4; ++j) {
        int r = wr0 + m * 16 + rj * 4 + j;
        float part = 0.f;
#pragma unroll
        for (int n = 0; n < 4; ++n) {
          int c = wc0 + n * 16 + cl;
          unsigned short eb = f2bf(exp2f(acc[m][n][j] * SC));
          E[(size_t)r * 2048 + c] = eb;
          part += __uint_as_float((unsigned)eb << 16);  // sum the rounded values
        }
#pragma unroll
        for (int o = 1; o < 16; o <<= 1) part += __shfl_xor(part, o);
        if (cl == 0) atomicAdd(&rs[r], part);
      }
    }
  } else {
#pragma unroll
    for (int m = 0; m < 4; ++m) {
#pragma unroll
      for (int n = 0; n < 4; ++n) {
#pragma unroll
        for (int j = 0; j < 4; ++j) {
          int r = wr0 + m * 16 + rj * 4 + j;
          int c = wc0 + n * 16 + cl;
          float val = acc[m][n][j];
          if constexpr (STORE == 0) {
            unsigned short* C = (unsigned short*)Cv + (size_t)bz * strideC;
            C[(size_t)r * ldc + c] = f2bf(val);
          } else if constexpr (STORE == 2) {
            unsigned short* C = (unsigned short*)Cv;
            size_t idx = ((size_t)(r >> 11) * 1024 + c) * 2048 + (size_t)(r & 2047);
            C[idx] = f2bf(val);
          } else {  // STORE == 4: PV, scale by 1/rowsum
            float* C = (float*)Cv + (size_t)bz * strideC;
            C[(size_t)r * ldc + c] = val * aux[bz * 2048 + r];
          }
        }
      }
    }
  }
}

extern "C" void kernel_launch(void* const* d_in, const int* in_sizes, int n_in,
                              void* d_out, int out_size, void* d_ws, size_t ws_size,
                              hipStream_t stream) {
  const float* x  = (const float*)d_in[0];
  const float* Wq = (const float*)d_in[1];
  const float* Wk = (const float*)d_in[2];
  const float* Wv = (const float*)d_in[3];

  char* w = (char*)d_ws;
  // ws: xb 16M | Wq,Wk 4M | Wv 2M | Q,K 32M | Vt 16M | E 32M | rowsum 32K (~102MB)
  unsigned short* xb  = (unsigned short*)(w);
  unsigned short* wqk = (unsigned short*)(w + (16ull << 20));
  unsigned short* wv  = (unsigned short*)(w + (20ull << 20));
  unsigned short* QK  = (unsigned short*)(w + (22ull << 20));  // Q then K, 8M elems each
  unsigned short* Vt  = (unsigned short*)(w + (54ull << 20));  // [b][o][s]
  unsigned short* E   = (unsigned short*)(w + (70ull << 20));  // [b][q][k] bf16 exp
  float*          rs  = (float*)        (w + (102ull << 20));  // [b][q] rowsum

  hipMemsetAsync(rs, 0, 8192 * sizeof(float), stream);

  // fp32 -> bf16
  cvt_bf16<<<8192, 256, 0, stream>>>(x,  xb);
  cvt_bf16<<<1024, 256, 0, stream>>>(Wq, wqk);
  cvt_bf16<<<1024, 256, 0, stream>>>(Wk, wqk + (1u << 20));
  cvt_bf16<<<1024, 256, 0, stream>>>(Wv, wv);

  // Q = x@Wq^T, K = x@Wk^T (z picks weight/output)
  gemm_nt<0><<<dim3(64, 8, 2), 256, 0, stream>>>(
      xb, wqk, QK, nullptr, 1024, 1024, 1024, 1024, 0, 1ll << 20, 8ll << 20);
  // V^T = (x@Wv^T)^T, stored [b][o][s]
  gemm_nt<2><<<dim3(64, 8, 1), 256, 0, stream>>>(
      xb, wv, Vt, nullptr, 1024, 1024, 0, 1024, 0, 0, 0);
  // E = exp2((Q@K^T)*log2e/32) per batch, bf16; rowsums accumulated atomically
  gemm_nt<3><<<dim3(16, 16, 4), 256, 0, stream>>>(
      QK, QK + (8u << 20), E, rs, 1024, 1024, 2048, 1024,
      2ll << 20, 2ll << 20, 0);
  invert8k<<<32, 256, 0, stream>>>(rs);
  // out = (E @ V^T) * (1/rowsum), f32 straight to d_out
  gemm_nt<4><<<dim3(16, 8, 4), 256, 0, stream>>>(
      E, Vt, d_out, rs, 2048, 2048, 1024, 2048,
      4ll << 20, 2ll << 20, 2ll << 20);
}